// Round 22
// baseline (123.811 us; speedup 1.0000x reference)
//
#include <hip/hip_runtime.h>
#include <hip/hip_fp16.h>

// ---------------------------------------------------------------------------
// 2-layer GCN on MI355X (R22).
//   prep:   fixed-capacity bucket scatter -> padded CSR(byte-offsets)
//           + rowinfo(beg,cnt) + dinv
//   layer:  hs = fp16((x@W) * dinv[row])   -- MFMA 16x16x32 f16 gemm
//           agg[i] = hs[i] + sum_{s->i} hs[s]  (R16 gather loop)
//           out = agg * dinv[i] + b (+relu)
// R22: (a) aggregate block 256 -> 1024 threads (16 waves/block, 3125 blocks;
// R21 agg showed OccupancyPercent 61% with VGPR=16 -> suspect CP packing of
// tiny blocks); (b) inter-layer hbuf fp32 -> fp16 (halves agg1-write +
// gemm2-read traffic; gemm2 A-frag becomes a single uint4 load).
// ---------------------------------------------------------------------------

#define NPB_SHIFT 7
#define NPB 128            // nodes per bucket
#define NBMAX 1024         // supports n <= 131072
#define EPB 4096           // edges per scatter block
#define KPB (EPB / 256)    // edges per thread in scatter block
#define EMAX 8192          // LDS csr staging capacity per bucket (padded)
#define CAP 4608           // fixed pairs capacity per bucket (mean+8sigma)
#define CSRSTRIDE 6656     // fixed csr segment per bucket (>= CAP + 128*15+16)

typedef _Float16 f16x8 __attribute__((ext_vector_type(8)));
typedef float f32x4 __attribute__((ext_vector_type(4)));
union F16x8 { f16x8 v; __half2 h[4]; uint4 u; };

__global__ __launch_bounds__(256) void zero_kernel(int* __restrict__ p, int m,
                                                   int* __restrict__ zrow) {
    int i = blockIdx.x * 256 + threadIdx.x;
    if (i < m) p[i] = 0;
    if (blockIdx.x == 0 && threadIdx.x < 32) zrow[threadIdx.x] = 0;   // 128B zero row
}

// Scatter packed edges pk = (src<<7)|(dst&127) into fixed-capacity bucket
// runs. bucketCur ends as per-bucket count.
__global__ __launch_bounds__(256) void bin_scatter_kernel(const int* __restrict__ src,
                                                          const int* __restrict__ dst, int E, int NB,
                                                          int* __restrict__ bucketCur,
                                                          int* __restrict__ pairs) {
    __shared__ int cntA[NBMAX];
    __shared__ int baseB[NBMAX];
    for (int i = threadIdx.x; i < NB; i += 256) cntA[i] = 0;
    __syncthreads();
    int base = blockIdx.x * EPB;
    int pk_[KPB], b_[KPB];
    #pragma unroll
    for (int k = 0; k < KPB; ++k) {
        int i = base + k * 256 + threadIdx.x;
        if (i < E) {
            int s = src[i], d = dst[i];
            pk_[k] = (s << NPB_SHIFT) | (d & (NPB - 1));
            b_[k] = d >> NPB_SHIFT;
            atomicAdd(&cntA[b_[k]], 1);
        } else {
            b_[k] = -1;
        }
    }
    __syncthreads();
    for (int i = threadIdx.x; i < NB; i += 256) {
        int c = cntA[i];
        baseB[i] = c ? atomicAdd(&bucketCur[i], c) : 0;
        cntA[i] = 0;
    }
    __syncthreads();
    #pragma unroll
    for (int k = 0; k < KPB; ++k) {
        if (b_[k] >= 0) {
            int off = atomicAdd(&cntA[b_[k]], 1);
            pairs[b_[k] * CAP + baseB[b_[k]] + off] = pk_[k];
        }
    }
}

// One block per bucket. Segments padded to multiples of 16 slots; pad slots
// hold the zero-row byte offset (n<<7). csr entry = pk & ~127 (= src<<7).
__global__ __launch_bounds__(256) void build_csr_kernel(const int* __restrict__ pairs,
                                                        const int* __restrict__ bucketCnt,
                                                        int NB, int n,
                                                        int2* __restrict__ rowinfo,
                                                        float* __restrict__ dinv,
                                                        int* __restrict__ csr) {
    __shared__ int deg[NPB];
    __shared__ int cur[NPB];
    __shared__ int rowL[NPB];      // padded exclusive prefix
    __shared__ int lcsr[EMAX];
    __shared__ int s_mP;
    int b = blockIdx.x;
    int nodeBase = b << NPB_SHIFT;
    int nNodes = min(NPB, n - nodeBase);
    int eBeg = b * CAP;
    int m = min(bucketCnt[b], CAP);
    int eEnd = eBeg + m;
    int Pb = b * CSRSTRIDE;
    for (int i = threadIdx.x; i < NPB; i += 256) { deg[i] = 0; cur[i] = 0; }
    __syncthreads();
    for (int e = eBeg + threadIdx.x; e < eEnd; e += 256)
        atomicAdd(&deg[pairs[e] & (NPB - 1)], 1);
    __syncthreads();
    if (threadIdx.x < 64) {
        int j0 = threadIdx.x * 2, j1 = j0 + 1;
        int p0 = (deg[j0] + 15) & ~15, p1 = (deg[j1] + 15) & ~15;
        int s = p0 + p1;
        int x = s;
        #pragma unroll
        for (int off = 1; off < 64; off <<= 1) {
            int y = __shfl_up(x, off);
            if ((int)threadIdx.x >= off) x += y;
        }
        int excl = x - s;
        rowL[j0] = excl;
        rowL[j1] = excl + p0;
        if (threadIdx.x == 63) s_mP = x;   // padded total
    }
    __syncthreads();
    int mP = s_mP;
    for (int j = threadIdx.x; j < nNodes; j += 256) {
        rowinfo[nodeBase + j] = make_int2(Pb + rowL[j], (deg[j] + 15) & ~15);
        dinv[nodeBase + j] = 1.0f / sqrtf((float)(deg[j] + 1));  // +1 self-loop
    }
    const int padEnt = n << NPB_SHIFT;   // zero-row byte offset
    if (mP <= EMAX) {
        for (int i = threadIdx.x; i < mP; i += 256) lcsr[i] = padEnt;
        __syncthreads();
        for (int e = eBeg + threadIdx.x; e < eEnd; e += 256) {
            int pk = pairs[e];
            int d = pk & (NPB - 1);
            int off = atomicAdd(&cur[d], 1);
            lcsr[rowL[d] + off] = pk & ~(NPB - 1);
        }
        __syncthreads();
        for (int i = threadIdx.x; i < mP; i += 256) csr[Pb + i] = lcsr[i];
    } else {  // overflow fallback (adversarial): direct global init + scatter
        for (int i = threadIdx.x; i < mP; i += 256) csr[Pb + i] = padEnt;
        __syncthreads();
        for (int e = eBeg + threadIdx.x; e < eEnd; e += 256) {
            int pk = pairs[e];
            int d = pk & (NPB - 1);
            int off = atomicAdd(&cur[d], 1);
            csr[Pb + rowL[d] + off] = pk & ~(NPB - 1);
        }
    }
}

// MFMA gemm: hs[r, c] = fp16( dinv[r] * sum_k X[r,k] * W[k,c] ), 64 cols.
// TIN = float (layer 1) or __half (layer 2: one uint4 load per A-frag).
// W staged transposed fp16 in LDS; B-frag = one ds_read_b128.
// D layout (m89-verified): col=lane&15, row=(lane>>4)*4+reg.
template <int K, typename TIN>
__global__ __launch_bounds__(256, 2) void gemm_scale_kernel(const TIN* __restrict__ X,
                                                            const float* __restrict__ W,
                                                            const float* __restrict__ dinv,
                                                            __half* __restrict__ out, int n) {
    __shared__ _Float16 Wt[64][K + 8];
    for (int idx = threadIdx.x; idx < K * 64; idx += 256) {
        int k = idx >> 6, c = idx & 63;
        Wt[c][k] = (_Float16)W[idx];
    }
    __syncthreads();

    const int lane = threadIdx.x & 63;
    const int wid  = threadIdx.x >> 6;
    const int l15  = lane & 15;
    const int lg   = lane >> 4;            // 0..3
    const int r0 = (blockIdx.x * 4 + wid) * 16;
    if (r0 >= n) return;

    F16x8 bfr[K / 32][4];
    #pragma unroll
    for (int kt = 0; kt < K / 32; ++kt)
        #pragma unroll
        for (int ct = 0; ct < 4; ++ct)
            bfr[kt][ct].u = *reinterpret_cast<const uint4*>(&Wt[ct * 16 + l15][kt * 32 + lg * 8]);

    f32x4 acc[4] = {{0.f, 0.f, 0.f, 0.f}, {0.f, 0.f, 0.f, 0.f},
                    {0.f, 0.f, 0.f, 0.f}, {0.f, 0.f, 0.f, 0.f}};
    const int arow = min(r0 + l15, n - 1);
    #pragma unroll
    for (int kt = 0; kt < K / 32; ++kt) {
        F16x8 a;
        if constexpr (sizeof(TIN) == 4) {
            const float4* xp = reinterpret_cast<const float4*>(
                (const float*)X + (size_t)arow * K + kt * 32 + lg * 8);
            float4 v0 = xp[0], v1 = xp[1];
            a.h[0] = __float22half2_rn(make_float2(v0.x, v0.y));
            a.h[1] = __float22half2_rn(make_float2(v0.z, v0.w));
            a.h[2] = __float22half2_rn(make_float2(v1.x, v1.y));
            a.h[3] = __float22half2_rn(make_float2(v1.z, v1.w));
        } else {
            a.u = *reinterpret_cast<const uint4*>(
                (const __half*)X + (size_t)arow * K + kt * 32 + lg * 8);
        }
        #pragma unroll
        for (int ct = 0; ct < 4; ++ct)
            acc[ct] = __builtin_amdgcn_mfma_f32_16x16x32_f16(a.v, bfr[kt][ct].v, acc[ct], 0, 0, 0);
    }

    float dv[4];
    #pragma unroll
    for (int i = 0; i < 4; ++i) dv[i] = dinv[min(r0 + lg * 4 + i, n - 1)];
    #pragma unroll
    for (int ct = 0; ct < 4; ++ct) {
        #pragma unroll
        for (int i = 0; i < 4; ++i) {
            int row = r0 + lg * 4 + i;
            if (row < n)
                out[(size_t)row * 64 + ct * 16 + l15] = __float2half_rn(acc[ct][i] * dv[i]);
        }
    }
}

// R16 aggregate loop, 1024-thread blocks (16 waves). One wave per node;
// half-wave = one 128B fp16 row per edge-slot; 16 slots/iter per half.
// TOUT = __half (layer 1 -> fp16 hbuf) or float (layer 2 -> d_out).
template <bool RELU, typename TOUT>
__global__ __launch_bounds__(1024) void aggregate_kernel(const __half* __restrict__ hs,
                                                         const int2* __restrict__ rowinfo,
                                                         const int* __restrict__ csr,
                                                         const float* __restrict__ dinv,
                                                         const float* __restrict__ bias,
                                                         TOUT* __restrict__ out, int n) {
    const int lane = threadIdx.x & 63;
    const int half = lane >> 5;
    const int l32  = lane & 31;
    const int wid  = threadIdx.x >> 6;     // 0..15
    int node = blockIdx.x * 16 + wid;
    if (node >= n) return;

    const char* hsb = (const char*)hs + l32 * 4;   // this lane's column-pair
    int2 info = rowinfo[node];
    const int* base = csr + info.x;
    const int cnt = info.y;                        // multiple of 16
    float a0 = 0.f, a1 = 0.f;
    for (int i = 16 * half; i < cnt; i += 32) {    // halves take alternate 16-blocks
        int4 c0 = *reinterpret_cast<const int4*>(base + i);
        int4 c1 = *reinterpret_cast<const int4*>(base + i + 4);
        int4 c2 = *reinterpret_cast<const int4*>(base + i + 8);
        int4 c3 = *reinterpret_cast<const int4*>(base + i + 12);
        float2 f0 = __half22float2(*(const __half2*)(hsb + c0.x));
        float2 f1 = __half22float2(*(const __half2*)(hsb + c0.y));
        float2 f2 = __half22float2(*(const __half2*)(hsb + c0.z));
        float2 f3 = __half22float2(*(const __half2*)(hsb + c0.w));
        float2 f4 = __half22float2(*(const __half2*)(hsb + c1.x));
        float2 f5 = __half22float2(*(const __half2*)(hsb + c1.y));
        float2 f6 = __half22float2(*(const __half2*)(hsb + c1.z));
        float2 f7 = __half22float2(*(const __half2*)(hsb + c1.w));
        float2 f8 = __half22float2(*(const __half2*)(hsb + c2.x));
        float2 f9 = __half22float2(*(const __half2*)(hsb + c2.y));
        float2 fa = __half22float2(*(const __half2*)(hsb + c2.z));
        float2 fb = __half22float2(*(const __half2*)(hsb + c2.w));
        float2 fc = __half22float2(*(const __half2*)(hsb + c3.x));
        float2 fd = __half22float2(*(const __half2*)(hsb + c3.y));
        float2 fe = __half22float2(*(const __half2*)(hsb + c3.z));
        float2 ff = __half22float2(*(const __half2*)(hsb + c3.w));
        a0 += (((f0.x + f1.x) + (f2.x + f3.x)) + ((f4.x + f5.x) + (f6.x + f7.x)))
            + (((f8.x + f9.x) + (fa.x + fb.x)) + ((fc.x + fd.x) + (fe.x + ff.x)));
        a1 += (((f0.y + f1.y) + (f2.y + f3.y)) + ((f4.y + f5.y) + (f6.y + f7.y)))
            + (((f8.y + f9.y) + (fa.y + fb.y)) + ((fc.y + fd.y) + (fe.y + ff.y)));
    }
    a0 += __shfl_xor(a0, 32);
    a1 += __shfl_xor(a1, 32);
    float2 fs = __half22float2(
        *(const __half2*)((const char*)hs + ((size_t)node << 7) + l32 * 4));
    a0 += fs.x;
    a1 += fs.y;

    if (half == 0) {
        float dv = dinv[node];
        float b0 = bias[2 * l32], b1 = bias[2 * l32 + 1];
        float r0 = fmaf(a0, dv, b0);
        float r1 = fmaf(a1, dv, b1);
        if (RELU) { r0 = fmaxf(r0, 0.f); r1 = fmaxf(r1, 0.f); }
        if constexpr (sizeof(TOUT) == 2) {
            *reinterpret_cast<__half2*>((__half*)out + (size_t)node * 64 + 2 * l32) =
                __float22half2_rn(make_float2(r0, r1));
        } else {
            *reinterpret_cast<float2*>((float*)out + (size_t)node * 64 + 2 * l32) =
                make_float2(r0, r1);
        }
    }
}

extern "C" void kernel_launch(void* const* d_in, const int* in_sizes, int n_in,
                              void* d_out, int out_size, void* d_ws, size_t ws_size,
                              hipStream_t stream) {
    const float* x  = (const float*)d_in[0];
    const int*   ei = (const int*)d_in[1];   // [2, E] int32
    const float* W1 = (const float*)d_in[2]; // [128, 64]
    const float* b1 = (const float*)d_in[3]; // [64]
    const float* W2 = (const float*)d_in[4]; // [64, 64]
    const float* b2 = (const float*)d_in[5]; // [64]
    float* out = (float*)d_out;

    const int E = in_sizes[1] / 2;   // 1,600,000
    const int n = out_size / 64;     // 50,000
    const int NB = (n + NPB - 1) >> NPB_SHIFT;   // 391 buckets

    char* wsp = (char*)d_ws;
    auto carve = [&](size_t bytes) {
        char* p = wsp;
        wsp += (bytes + 255) & ~(size_t)255;
        return p;
    };
    float*  dinv      = (float*)carve((size_t)n * 4);
    int2*   rowinfo   = (int2*) carve((size_t)n * 8);
    int*    bucketCur = (int*)  carve((size_t)NBMAX * 4);
    int*    csr       = (int*)  carve((size_t)NB * CSRSTRIDE * 4);
    size_t  pairBytes = ((size_t)NB + 1) * CAP * 4;      // +1 bucket overflow slack
    size_t  featF16   = (size_t)n * 64 * 2;
    size_t  bigBytes  = pairBytes > featF16 ? pairBytes : featF16;
    char*   big       = (char*)carve(bigBytes);          // packed pairs, later hbuf (fp16)
    int*    pairs     = (int*)big;
    __half* hbuf      = (__half*)big;                    // pairs dead by then
    __half* hsbuf     = (__half*)carve((size_t)(n + 1) * 64 * 2);  // +1 zero row

    const int* srcIdx = ei;
    const int* dstIdx = ei + E;
    const int scatterBlocks = (E + EPB - 1) / EPB;  // 391
    const int gemmBlocks = (n + 63) / 64;           // 782 (64 rows/block)
    const int aggBlocks = (n + 15) / 16;            // 3125 (16 nodes/block)

    // --- prep: fixed-capacity bucket scatter -> padded csr, rowinfo, dinv ---
    zero_kernel<<<(NBMAX + 255) / 256, 256, 0, stream>>>(bucketCur, NBMAX,
                                                         (int*)(hsbuf + (size_t)n * 64));
    bin_scatter_kernel<<<scatterBlocks, 256, 0, stream>>>(srcIdx, dstIdx, E, NB, bucketCur, pairs);
    build_csr_kernel<<<NB, 256, 0, stream>>>(pairs, bucketCur, NB, n, rowinfo, dinv, csr);

    // --- layer 1: relu(gcn_conv(x, W1, b1)) -> hbuf (fp16) ---
    gemm_scale_kernel<128, float><<<gemmBlocks, 256, 0, stream>>>(x, W1, dinv, hsbuf, n);
    aggregate_kernel<true, __half><<<aggBlocks, 1024, 0, stream>>>(hsbuf, rowinfo, csr, dinv,
                                                                   b1, hbuf, n);

    // --- layer 2: gcn_conv(hbuf, W2, b2) -> out ---
    gemm_scale_kernel<64, __half><<<gemmBlocks, 256, 0, stream>>>(hbuf, W2, dinv, hsbuf, n);
    aggregate_kernel<false, float><<<aggBlocks, 1024, 0, stream>>>(hsbuf, rowinfo, csr, dinv,
                                                                   b2, out, n);
}

// Round 26
// 115.268 us; speedup vs baseline: 1.0741x; 1.0741x over previous
//
#include <hip/hip_runtime.h>
#include <hip/hip_fp16.h>

// ---------------------------------------------------------------------------
// 2-layer GCN on MI355X (R23, resubmit #3 after infra flakes).
//   prep:   fixed-capacity bucket scatter -> padded CSR(byte-offsets)
//           + rowinfo(beg,cnt) + dinv
//   layer:  hs = fp16((x@W) * dinv[row])   -- MFMA 16x16x32 f16 gemm
//           agg[i] = hs[i] + sum_{s->i} hs[s]  (R16 gather loop, 256-thr)
//           out = agg * dinv[i] + b (+relu)
// R23: single-variable revert of R22's regression (+7.7us): agg blocks back
// to 256 threads (R21-best shape; 1024-thr blocks coarsened CU packing),
// KEEPING fp16 hbuf (traffic-reducing). Attributes both R22 changes.
// ---------------------------------------------------------------------------

#define NPB_SHIFT 7
#define NPB 128            // nodes per bucket
#define NBMAX 1024         // supports n <= 131072
#define EPB 4096           // edges per scatter block
#define KPB (EPB / 256)    // edges per thread in scatter block
#define EMAX 8192          // LDS csr staging capacity per bucket (padded)
#define CAP 4608           // fixed pairs capacity per bucket (mean+8sigma)
#define CSRSTRIDE 6656     // fixed csr segment per bucket (>= CAP + 128*15+16)

typedef _Float16 f16x8 __attribute__((ext_vector_type(8)));
typedef float f32x4 __attribute__((ext_vector_type(4)));
union F16x8 { f16x8 v; __half2 h[4]; uint4 u; };

__global__ __launch_bounds__(256) void zero_kernel(int* __restrict__ p, int m,
                                                   int* __restrict__ zrow) {
    int i = blockIdx.x * 256 + threadIdx.x;
    if (i < m) p[i] = 0;
    if (blockIdx.x == 0 && threadIdx.x < 32) zrow[threadIdx.x] = 0;   // 128B zero row
}

// Scatter packed edges pk = (src<<7)|(dst&127) into fixed-capacity bucket
// runs. bucketCur ends as per-bucket count.
__global__ __launch_bounds__(256) void bin_scatter_kernel(const int* __restrict__ src,
                                                          const int* __restrict__ dst, int E, int NB,
                                                          int* __restrict__ bucketCur,
                                                          int* __restrict__ pairs) {
    __shared__ int cntA[NBMAX];
    __shared__ int baseB[NBMAX];
    for (int i = threadIdx.x; i < NB; i += 256) cntA[i] = 0;
    __syncthreads();
    int base = blockIdx.x * EPB;
    int pk_[KPB], b_[KPB];
    #pragma unroll
    for (int k = 0; k < KPB; ++k) {
        int i = base + k * 256 + threadIdx.x;
        if (i < E) {
            int s = src[i], d = dst[i];
            pk_[k] = (s << NPB_SHIFT) | (d & (NPB - 1));
            b_[k] = d >> NPB_SHIFT;
            atomicAdd(&cntA[b_[k]], 1);
        } else {
            b_[k] = -1;
        }
    }
    __syncthreads();
    for (int i = threadIdx.x; i < NB; i += 256) {
        int c = cntA[i];
        baseB[i] = c ? atomicAdd(&bucketCur[i], c) : 0;
        cntA[i] = 0;
    }
    __syncthreads();
    #pragma unroll
    for (int k = 0; k < KPB; ++k) {
        if (b_[k] >= 0) {
            int off = atomicAdd(&cntA[b_[k]], 1);
            pairs[b_[k] * CAP + baseB[b_[k]] + off] = pk_[k];
        }
    }
}

// One block per bucket. Segments padded to multiples of 16 slots; pad slots
// hold the zero-row byte offset (n<<7). csr entry = pk & ~127 (= src<<7).
__global__ __launch_bounds__(256) void build_csr_kernel(const int* __restrict__ pairs,
                                                        const int* __restrict__ bucketCnt,
                                                        int NB, int n,
                                                        int2* __restrict__ rowinfo,
                                                        float* __restrict__ dinv,
                                                        int* __restrict__ csr) {
    __shared__ int deg[NPB];
    __shared__ int cur[NPB];
    __shared__ int rowL[NPB];      // padded exclusive prefix
    __shared__ int lcsr[EMAX];
    __shared__ int s_mP;
    int b = blockIdx.x;
    int nodeBase = b << NPB_SHIFT;
    int nNodes = min(NPB, n - nodeBase);
    int eBeg = b * CAP;
    int m = min(bucketCnt[b], CAP);
    int eEnd = eBeg + m;
    int Pb = b * CSRSTRIDE;
    for (int i = threadIdx.x; i < NPB; i += 256) { deg[i] = 0; cur[i] = 0; }
    __syncthreads();
    for (int e = eBeg + threadIdx.x; e < eEnd; e += 256)
        atomicAdd(&deg[pairs[e] & (NPB - 1)], 1);
    __syncthreads();
    if (threadIdx.x < 64) {
        int j0 = threadIdx.x * 2, j1 = j0 + 1;
        int p0 = (deg[j0] + 15) & ~15, p1 = (deg[j1] + 15) & ~15;
        int s = p0 + p1;
        int x = s;
        #pragma unroll
        for (int off = 1; off < 64; off <<= 1) {
            int y = __shfl_up(x, off);
            if ((int)threadIdx.x >= off) x += y;
        }
        int excl = x - s;
        rowL[j0] = excl;
        rowL[j1] = excl + p0;
        if (threadIdx.x == 63) s_mP = x;   // padded total
    }
    __syncthreads();
    int mP = s_mP;
    for (int j = threadIdx.x; j < nNodes; j += 256) {
        rowinfo[nodeBase + j] = make_int2(Pb + rowL[j], (deg[j] + 15) & ~15);
        dinv[nodeBase + j] = 1.0f / sqrtf((float)(deg[j] + 1));  // +1 self-loop
    }
    const int padEnt = n << NPB_SHIFT;   // zero-row byte offset
    if (mP <= EMAX) {
        for (int i = threadIdx.x; i < mP; i += 256) lcsr[i] = padEnt;
        __syncthreads();
        for (int e = eBeg + threadIdx.x; e < eEnd; e += 256) {
            int pk = pairs[e];
            int d = pk & (NPB - 1);
            int off = atomicAdd(&cur[d], 1);
            lcsr[rowL[d] + off] = pk & ~(NPB - 1);
        }
        __syncthreads();
        for (int i = threadIdx.x; i < mP; i += 256) csr[Pb + i] = lcsr[i];
    } else {  // overflow fallback (adversarial): direct global init + scatter
        for (int i = threadIdx.x; i < mP; i += 256) csr[Pb + i] = padEnt;
        __syncthreads();
        for (int e = eBeg + threadIdx.x; e < eEnd; e += 256) {
            int pk = pairs[e];
            int d = pk & (NPB - 1);
            int off = atomicAdd(&cur[d], 1);
            csr[Pb + rowL[d] + off] = pk & ~(NPB - 1);
        }
    }
}

// MFMA gemm: hs[r, c] = fp16( dinv[r] * sum_k X[r,k] * W[k,c] ), 64 cols.
// TIN = float (layer 1) or __half (layer 2: one uint4 load per A-frag).
// W staged transposed fp16 in LDS; B-frag = one ds_read_b128.
// D layout (m89-verified): col=lane&15, row=(lane>>4)*4+reg.
template <int K, typename TIN>
__global__ __launch_bounds__(256, 2) void gemm_scale_kernel(const TIN* __restrict__ X,
                                                            const float* __restrict__ W,
                                                            const float* __restrict__ dinv,
                                                            __half* __restrict__ out, int n) {
    __shared__ _Float16 Wt[64][K + 8];
    for (int idx = threadIdx.x; idx < K * 64; idx += 256) {
        int k = idx >> 6, c = idx & 63;
        Wt[c][k] = (_Float16)W[idx];
    }
    __syncthreads();

    const int lane = threadIdx.x & 63;
    const int wid  = threadIdx.x >> 6;
    const int l15  = lane & 15;
    const int lg   = lane >> 4;            // 0..3
    const int r0 = (blockIdx.x * 4 + wid) * 16;
    if (r0 >= n) return;

    F16x8 bfr[K / 32][4];
    #pragma unroll
    for (int kt = 0; kt < K / 32; ++kt)
        #pragma unroll
        for (int ct = 0; ct < 4; ++ct)
            bfr[kt][ct].u = *reinterpret_cast<const uint4*>(&Wt[ct * 16 + l15][kt * 32 + lg * 8]);

    f32x4 acc[4] = {{0.f, 0.f, 0.f, 0.f}, {0.f, 0.f, 0.f, 0.f},
                    {0.f, 0.f, 0.f, 0.f}, {0.f, 0.f, 0.f, 0.f}};
    const int arow = min(r0 + l15, n - 1);
    #pragma unroll
    for (int kt = 0; kt < K / 32; ++kt) {
        F16x8 a;
        if constexpr (sizeof(TIN) == 4) {
            const float4* xp = reinterpret_cast<const float4*>(
                (const float*)X + (size_t)arow * K + kt * 32 + lg * 8);
            float4 v0 = xp[0], v1 = xp[1];
            a.h[0] = __float22half2_rn(make_float2(v0.x, v0.y));
            a.h[1] = __float22half2_rn(make_float2(v0.z, v0.w));
            a.h[2] = __float22half2_rn(make_float2(v1.x, v1.y));
            a.h[3] = __float22half2_rn(make_float2(v1.z, v1.w));
        } else {
            a.u = *reinterpret_cast<const uint4*>(
                (const __half*)X + (size_t)arow * K + kt * 32 + lg * 8);
        }
        #pragma unroll
        for (int ct = 0; ct < 4; ++ct)
            acc[ct] = __builtin_amdgcn_mfma_f32_16x16x32_f16(a.v, bfr[kt][ct].v, acc[ct], 0, 0, 0);
    }

    float dv[4];
    #pragma unroll
    for (int i = 0; i < 4; ++i) dv[i] = dinv[min(r0 + lg * 4 + i, n - 1)];
    #pragma unroll
    for (int ct = 0; ct < 4; ++ct) {
        #pragma unroll
        for (int i = 0; i < 4; ++i) {
            int row = r0 + lg * 4 + i;
            if (row < n)
                out[(size_t)row * 64 + ct * 16 + l15] = __float2half_rn(acc[ct][i] * dv[i]);
        }
    }
}

// R16/R21 aggregate: 256-thread blocks, one wave per node; half-wave = one
// 128B fp16 row per edge-slot; 16 slots/iter per half (4 int4 + 16 gathers).
// TOUT = __half (layer 1 -> fp16 hbuf) or float (layer 2 -> d_out).
template <bool RELU, typename TOUT>
__global__ __launch_bounds__(256) void aggregate_kernel(const __half* __restrict__ hs,
                                                        const int2* __restrict__ rowinfo,
                                                        const int* __restrict__ csr,
                                                        const float* __restrict__ dinv,
                                                        const float* __restrict__ bias,
                                                        TOUT* __restrict__ out, int n) {
    const int lane = threadIdx.x & 63;
    const int half = lane >> 5;
    const int l32  = lane & 31;
    const int wid  = threadIdx.x >> 6;
    int node = blockIdx.x * 4 + wid;
    if (node >= n) return;

    const char* hsb = (const char*)hs + l32 * 4;   // this lane's column-pair
    int2 info = rowinfo[node];
    const int* base = csr + info.x;
    const int cnt = info.y;                        // multiple of 16
    float a0 = 0.f, a1 = 0.f;
    for (int i = 16 * half; i < cnt; i += 32) {    // halves take alternate 16-blocks
        int4 c0 = *reinterpret_cast<const int4*>(base + i);
        int4 c1 = *reinterpret_cast<const int4*>(base + i + 4);
        int4 c2 = *reinterpret_cast<const int4*>(base + i + 8);
        int4 c3 = *reinterpret_cast<const int4*>(base + i + 12);
        float2 f0 = __half22float2(*(const __half2*)(hsb + c0.x));
        float2 f1 = __half22float2(*(const __half2*)(hsb + c0.y));
        float2 f2 = __half22float2(*(const __half2*)(hsb + c0.z));
        float2 f3 = __half22float2(*(const __half2*)(hsb + c0.w));
        float2 f4 = __half22float2(*(const __half2*)(hsb + c1.x));
        float2 f5 = __half22float2(*(const __half2*)(hsb + c1.y));
        float2 f6 = __half22float2(*(const __half2*)(hsb + c1.z));
        float2 f7 = __half22float2(*(const __half2*)(hsb + c1.w));
        float2 f8 = __half22float2(*(const __half2*)(hsb + c2.x));
        float2 f9 = __half22float2(*(const __half2*)(hsb + c2.y));
        float2 fa = __half22float2(*(const __half2*)(hsb + c2.z));
        float2 fb = __half22float2(*(const __half2*)(hsb + c2.w));
        float2 fc = __half22float2(*(const __half2*)(hsb + c3.x));
        float2 fd = __half22float2(*(const __half2*)(hsb + c3.y));
        float2 fe = __half22float2(*(const __half2*)(hsb + c3.z));
        float2 ff = __half22float2(*(const __half2*)(hsb + c3.w));
        a0 += (((f0.x + f1.x) + (f2.x + f3.x)) + ((f4.x + f5.x) + (f6.x + f7.x)))
            + (((f8.x + f9.x) + (fa.x + fb.x)) + ((fc.x + fd.x) + (fe.x + ff.x)));
        a1 += (((f0.y + f1.y) + (f2.y + f3.y)) + ((f4.y + f5.y) + (f6.y + f7.y)))
            + (((f8.y + f9.y) + (fa.y + fb.y)) + ((fc.y + fd.y) + (fe.y + ff.y)));
    }
    a0 += __shfl_xor(a0, 32);
    a1 += __shfl_xor(a1, 32);
    float2 fs = __half22float2(
        *(const __half2*)((const char*)hs + ((size_t)node << 7) + l32 * 4));
    a0 += fs.x;
    a1 += fs.y;

    if (half == 0) {
        float dv = dinv[node];
        float b0 = bias[2 * l32], b1 = bias[2 * l32 + 1];
        float r0 = fmaf(a0, dv, b0);
        float r1 = fmaf(a1, dv, b1);
        if (RELU) { r0 = fmaxf(r0, 0.f); r1 = fmaxf(r1, 0.f); }
        if constexpr (sizeof(TOUT) == 2) {
            *reinterpret_cast<__half2*>((__half*)out + (size_t)node * 64 + 2 * l32) =
                __float22half2_rn(make_float2(r0, r1));
        } else {
            *reinterpret_cast<float2*>((float*)out + (size_t)node * 64 + 2 * l32) =
                make_float2(r0, r1);
        }
    }
}

extern "C" void kernel_launch(void* const* d_in, const int* in_sizes, int n_in,
                              void* d_out, int out_size, void* d_ws, size_t ws_size,
                              hipStream_t stream) {
    const float* x  = (const float*)d_in[0];
    const int*   ei = (const int*)d_in[1];   // [2, E] int32
    const float* W1 = (const float*)d_in[2]; // [128, 64]
    const float* b1 = (const float*)d_in[3]; // [64]
    const float* W2 = (const float*)d_in[4]; // [64, 64]
    const float* b2 = (const float*)d_in[5]; // [64]
    float* out = (float*)d_out;

    const int E = in_sizes[1] / 2;   // 1,600,000
    const int n = out_size / 64;     // 50,000
    const int NB = (n + NPB - 1) >> NPB_SHIFT;   // 391 buckets

    char* wsp = (char*)d_ws;
    auto carve = [&](size_t bytes) {
        char* p = wsp;
        wsp += (bytes + 255) & ~(size_t)255;
        return p;
    };
    float*  dinv      = (float*)carve((size_t)n * 4);
    int2*   rowinfo   = (int2*) carve((size_t)n * 8);
    int*    bucketCur = (int*)  carve((size_t)NBMAX * 4);
    int*    csr       = (int*)  carve((size_t)NB * CSRSTRIDE * 4);
    size_t  pairBytes = ((size_t)NB + 1) * CAP * 4;      // +1 bucket overflow slack
    size_t  featF16   = (size_t)n * 64 * 2;
    size_t  bigBytes  = pairBytes > featF16 ? pairBytes : featF16;
    char*   big       = (char*)carve(bigBytes);          // packed pairs, later hbuf (fp16)
    int*    pairs     = (int*)big;
    __half* hbuf      = (__half*)big;                    // pairs dead by then
    __half* hsbuf     = (__half*)carve((size_t)(n + 1) * 64 * 2);  // +1 zero row

    const int* srcIdx = ei;
    const int* dstIdx = ei + E;
    const int scatterBlocks = (E + EPB - 1) / EPB;  // 391
    const int gemmBlocks = (n + 63) / 64;           // 782 (64 rows/block)
    const int aggBlocks = (n + 3) / 4;              // 12500 (4 nodes/block)

    // --- prep: fixed-capacity bucket scatter -> padded csr, rowinfo, dinv ---
    zero_kernel<<<(NBMAX + 255) / 256, 256, 0, stream>>>(bucketCur, NBMAX,
                                                         (int*)(hsbuf + (size_t)n * 64));
    bin_scatter_kernel<<<scatterBlocks, 256, 0, stream>>>(srcIdx, dstIdx, E, NB, bucketCur, pairs);
    build_csr_kernel<<<NB, 256, 0, stream>>>(pairs, bucketCur, NB, n, rowinfo, dinv, csr);

    // --- layer 1: relu(gcn_conv(x, W1, b1)) -> hbuf (fp16) ---
    gemm_scale_kernel<128, float><<<gemmBlocks, 256, 0, stream>>>(x, W1, dinv, hsbuf, n);
    aggregate_kernel<true, __half><<<aggBlocks, 256, 0, stream>>>(hsbuf, rowinfo, csr, dinv,
                                                                  b1, hbuf, n);

    // --- layer 2: gcn_conv(hbuf, W2, b2) -> out ---
    gemm_scale_kernel<64, __half><<<gemmBlocks, 256, 0, stream>>>(hbuf, W2, dinv, hsbuf, n);
    aggregate_kernel<false, float><<<aggBlocks, 256, 0, stream>>>(hsbuf, rowinfo, csr, dinv,
                                                                  b2, out, n);
}